// Round 6
// baseline (591.275 us; speedup 1.0000x reference)
//
#include <hip/hip_runtime.h>

// Problem constants (match reference)
constexpr int NGPH = 128;            // graphs per batch
constexpr int NPG  = 1024;           // nodes per graph
constexpr int NN   = NGPH * NPG;     // 131072 nodes
constexpr int HD   = 128;            // feature width (FIN == H == 128)
constexpr int EPG  = 16384;          // edges per graph (E // B), contiguous per graph
constexpr int KS1 = 820, KS2 = 656, KS3 = 525;

typedef _Float16 half8v __attribute__((ext_vector_type(8)));
typedef float f32x4 __attribute__((ext_vector_type(4)));

// ---------------------------------------------------------------------------
// gate = 1.0 for all nodes (ws is poisoned 0xAA before each call).
__global__ __launch_bounds__(256) void init_gate(float* __restrict__ gate) {
  int i = blockIdx.x * 256 + threadIdx.x;
  if (i < NN) gate[i] = 1.0f;
}

// ---------------------------------------------------------------------------
// Convert all 3 layers' [Wl|Wr] (fp32) to fp16 hi/lo planes:
// Wc[layer][plane][n][k], plane 0 = hi, 1 = lo; k<128 -> Wl, k>=128 -> Wr.
__global__ __launch_bounds__(256) void wconv(const float* __restrict__ Wl0, const float* __restrict__ Wr0,
                                             const float* __restrict__ Wl1, const float* __restrict__ Wr1,
                                             const float* __restrict__ Wl2, const float* __restrict__ Wr2,
                                             _Float16* __restrict__ Wc) {
  int tid = blockIdx.x * 256 + threadIdx.x;      // 3*32768
  int layer = tid >> 15;
  int idx = tid & 32767;
  int n = idx >> 8, k = idx & 255;
  const float* Wlp = layer == 0 ? Wl0 : layer == 1 ? Wl1 : Wl2;
  const float* Wrp = layer == 0 ? Wr0 : layer == 1 ? Wr1 : Wr2;
  float v = (k < 128) ? Wlp[n * 128 + k] : Wrp[n * 128 + k - 128];
  _Float16 h = (_Float16)v;
  _Float16 l = (_Float16)(v - (float)h);
  size_t base = (size_t)layer * 65536;
  Wc[base + (size_t)n * 256 + k] = h;
  Wc[base + 32768 + (size_t)n * 256 + k] = l;
}

// ---------------------------------------------------------------------------
// Build per-graph incoming-CSR (counting sort by dst). One block per graph.
// Output overwrites the graph's own src-half of edge_index (dead afterwards;
// harness restores d_in before every launch):
//   [g*64KB, +32KB) : src_sorted ushort[16384];  [+32KB, +2KB) : rs ushort[1024]
__global__ __launch_bounds__(512) void csr_build(int* __restrict__ ei) {
  __shared__ unsigned int ed[EPG];   // packed src | dst<<10  (64 KB)
  __shared__ int cnt[NPG];
  __shared__ int scn[NPG];
  __shared__ int off[NPG];
  int g = blockIdx.x, t = threadIdx.x;
  const int* srcg = ei + (size_t)g * EPG;
  const int* dstg = ei + (size_t)NGPH * EPG + (size_t)g * EPG;
  for (int i = t; i < EPG; i += 512) {
    unsigned int s = (unsigned int)(srcg[i] - (g << 10));
    unsigned int d = (unsigned int)(dstg[i] - (g << 10));
    ed[i] = s | (d << 10);
  }
  for (int i = t; i < NPG; i += 512) cnt[i] = 0;
  __syncthreads();
  for (int i = t; i < EPG; i += 512) atomicAdd(&cnt[ed[i] >> 10], 1);
  __syncthreads();
  int* a = cnt; int* b = scn;
  for (int d = 1; d < NPG; d <<= 1) {
    for (int i = t; i < NPG; i += 512) b[i] = a[i] + (i >= d ? a[i - d] : 0);
    __syncthreads();
    int* tmp = a; a = b; b = tmp;
  }
  unsigned short* ssort = (unsigned short*)(ei + (size_t)g * EPG);
  unsigned short* rsout = ssort + EPG;
  for (int r = t; r < NPG; r += 512) {
    int ex = r ? a[r - 1] : 0;
    rsout[r] = (unsigned short)ex;
    off[r] = ex;
  }
  __syncthreads();
  for (int i = t; i < EPG; i += 512) {
    unsigned int e = ed[i];
    int pos = atomicAdd(&off[e >> 10], 1);
    ssort[pos] = (unsigned short)(e & 1023u);
  }
}

// ---------------------------------------------------------------------------
// Mean aggregation via CSR gather, gate[src] applied on the fly, deg fused.
// XCD swizzle keeps each graph's 512 KB slice L2-resident. Inner loop
// unrolled 8: 8 independent dwordx4 gathers in flight per 32-lane group.
__global__ __launch_bounds__(256) void agg2_kernel(const float* __restrict__ X,
                                                   const int* __restrict__ ei,
                                                   const float* __restrict__ gate,
                                                   float* __restrict__ Mout) {
  int t = threadIdx.x;
  int xcd = blockIdx.x & 7, q = blockIdx.x >> 3;
  int g = ((q >> 7) << 3) + xcd;
  int r = (q & 127) * 8 + (t >> 5);
  int lane = t & 31;
  const unsigned short* ss  = (const unsigned short*)(ei + (size_t)g * EPG);
  const unsigned short* rsg = ss + EPG;
  int start = rsg[r];
  int end   = (r < 1023) ? (int)rsg[r + 1] : EPG;
  const float4* X4 = (const float4*)X;
  size_t gb4 = (size_t)(g << 10) * 32;
  float4 acc = make_float4(0.f, 0.f, 0.f, 0.f);
  float degf = 0.f;
  for (int base = start; base < end; base += 32) {
    int ec = end - base; if (ec > 32) ec = 32;
    int sl = 0; float gv = 0.f;
    if (lane < ec) {
      sl = ss[base + lane];
      gv = gate[(g << 10) + sl];
    }
    degf += (gv != 0.f) ? 1.f : 0.f;
    int e = 0;
    for (; e + 8 <= ec; e += 8) {
      int s[8]; float gg[8]; float4 v[8];
#pragma unroll
      for (int k = 0; k < 8; ++k) { s[k] = __shfl(sl, e + k, 32); gg[k] = __shfl(gv, e + k, 32); }
#pragma unroll
      for (int k = 0; k < 8; ++k) v[k] = X4[gb4 + (size_t)s[k] * 32 + lane];
#pragma unroll
      for (int k = 0; k < 8; ++k) {
        acc.x += v[k].x * gg[k]; acc.y += v[k].y * gg[k];
        acc.z += v[k].z * gg[k]; acc.w += v[k].w * gg[k];
      }
    }
    for (; e + 4 <= ec; e += 4) {
      int s[4]; float gg[4]; float4 v[4];
#pragma unroll
      for (int k = 0; k < 4; ++k) { s[k] = __shfl(sl, e + k, 32); gg[k] = __shfl(gv, e + k, 32); }
#pragma unroll
      for (int k = 0; k < 4; ++k) v[k] = X4[gb4 + (size_t)s[k] * 32 + lane];
#pragma unroll
      for (int k = 0; k < 4; ++k) {
        acc.x += v[k].x * gg[k]; acc.y += v[k].y * gg[k];
        acc.z += v[k].z * gg[k]; acc.w += v[k].w * gg[k];
      }
    }
    for (; e < ec; ++e) {
      int s0 = __shfl(sl, e, 32);
      float g0 = __shfl(gv, e, 32);
      float4 v0 = X4[gb4 + (size_t)s0 * 32 + lane];
      acc.x += v0.x * g0; acc.y += v0.y * g0;
      acc.z += v0.z * g0; acc.w += v0.w * g0;
    }
  }
#pragma unroll
  for (int m = 1; m <= 16; m <<= 1) degf += __shfl_xor(degf, m, 32);
  float inv = 1.0f / fmaxf(degf, 1.0f);
  acc.x *= inv; acc.y *= inv; acc.z *= inv; acc.w *= inv;
  ((float4*)Mout)[(size_t)((g << 10) + r) * 32 + lane] = acc;
}

// ---------------------------------------------------------------------------
// Hout = relu( S @ Wl^T + (X*gate) @ Wr^T + bias ) via fp16-split MFMA, plus
// fused score[node] = relu(H).wp. W pre-converted to fp16 hi/lo planes (Wc).
// 128x128 tile/block, 4 waves 2x2, each 64x64 as 4x4 of 16x16x32 f16 MFMAs,
// products hh+hl+lh. LDA=34 (odd 17-bank stride) + b128 staging writes;
// 34.5 KB LDS + <=128 VGPR -> 4 blocks/CU, grid 1024 fully resident.
constexpr int LDA = 34;   // fp16 elements per LDS row (32 + 2 pad)
__global__ __launch_bounds__(256, 4) void gemm_mfma(const float* S,
                                                    const float* __restrict__ X,
                                                    const _Float16* __restrict__ Wc,
                                                    const float* __restrict__ bb,
                                                    const float* __restrict__ wp,
                                                    const float* __restrict__ gate,
                                                    float* Hout,
                                                    float* __restrict__ score) {
  __shared__ _Float16 Ah[128 * LDA];
  __shared__ _Float16 Al[128 * LDA];
  __shared__ _Float16 Bh[128 * LDA];
  __shared__ _Float16 Bl[128 * LDA];
  __shared__ float sc_s[128];
  int t = threadIdx.x;
  int r0 = blockIdx.x * 128;
  int lane = t & 63, wid = t >> 6;
  int wm = wid & 1, wn = wid >> 1;
  int quad = lane >> 4, mr = lane & 15;
  const _Float16* WH = Wc;
  const _Float16* WL = Wc + 32768;

  f32x4 acc[4][4];
#pragma unroll
  for (int i = 0; i < 4; ++i)
#pragma unroll
    for (int j = 0; j < 4; ++j) acc[i][j] = (f32x4){0.f, 0.f, 0.f, 0.f};

  for (int ks = 0; ks < 256; ks += 32) {
    bool isS = (ks < 128);
    // ---- stage A (fp32 -> hi/lo fp16), 128 rows x 32 k, b128 writes
    const float* Asrc = isS ? (S + (size_t)r0 * HD + ks)
                            : (X + (size_t)r0 * HD + (ks - 128));
#pragma unroll
    for (int i = 0; i < 2; ++i) {
      int slot = t + i * 256;          // 0..511, 8 floats each
      int row = slot >> 2;
      int kq = (slot & 3) * 8;
      float4 v0 = *(const float4*)&Asrc[(size_t)row * HD + kq];
      float4 v1 = *(const float4*)&Asrc[(size_t)row * HD + kq + 4];
      if (!isS) {
        float gv = gate[r0 + row];
        v0.x *= gv; v0.y *= gv; v0.z *= gv; v0.w *= gv;
        v1.x *= gv; v1.y *= gv; v1.z *= gv; v1.w *= gv;
      }
      half8v h, l;
      h[0] = (_Float16)v0.x; h[1] = (_Float16)v0.y; h[2] = (_Float16)v0.z; h[3] = (_Float16)v0.w;
      h[4] = (_Float16)v1.x; h[5] = (_Float16)v1.y; h[6] = (_Float16)v1.z; h[7] = (_Float16)v1.w;
      l[0] = (_Float16)(v0.x - (float)h[0]); l[1] = (_Float16)(v0.y - (float)h[1]);
      l[2] = (_Float16)(v0.z - (float)h[2]); l[3] = (_Float16)(v0.w - (float)h[3]);
      l[4] = (_Float16)(v1.x - (float)h[4]); l[5] = (_Float16)(v1.y - (float)h[5]);
      l[6] = (_Float16)(v1.z - (float)h[6]); l[7] = (_Float16)(v1.w - (float)h[7]);
      *(half8v*)&Ah[row * LDA + kq] = h;
      *(half8v*)&Al[row * LDA + kq] = l;
    }
    // ---- stage B (pre-converted fp16 planes), b128 copies
#pragma unroll
    for (int i = 0; i < 2; ++i) {
      int slot = t + i * 256;
      int n = slot >> 2;
      int kq = (slot & 3) * 8;
      *(half8v*)&Bh[n * LDA + kq] = *(const half8v*)&WH[(size_t)n * 256 + ks + kq];
      *(half8v*)&Bl[n * LDA + kq] = *(const half8v*)&WL[(size_t)n * 256 + ks + kq];
    }
    __syncthreads();
    // ---- fragments + MFMA
    half8v af[4], alf[4], bf[4], blf[4];
#pragma unroll
    for (int i = 0; i < 4; ++i) {
      int rowA = (wm * 64 + i * 16 + mr) * LDA + quad * 8;
      af[i]  = *(const half8v*)&Ah[rowA];
      alf[i] = *(const half8v*)&Al[rowA];
    }
#pragma unroll
    for (int j = 0; j < 4; ++j) {
      int rowW = (wn * 64 + j * 16 + mr) * LDA + quad * 8;
      bf[j]  = *(const half8v*)&Bh[rowW];
      blf[j] = *(const half8v*)&Bl[rowW];
    }
#pragma unroll
    for (int i = 0; i < 4; ++i)
#pragma unroll
      for (int j = 0; j < 4; ++j) {
        acc[i][j] = __builtin_amdgcn_mfma_f32_16x16x32_f16(af[i],  bf[j],  acc[i][j], 0, 0, 0);
        acc[i][j] = __builtin_amdgcn_mfma_f32_16x16x32_f16(af[i],  blf[j], acc[i][j], 0, 0, 0);
        acc[i][j] = __builtin_amdgcn_mfma_f32_16x16x32_f16(alf[i], bf[j],  acc[i][j], 0, 0, 0);
      }
    __syncthreads();
  }
  // ---- epilogue: bias + relu + H store + fused score = relu(H).wp
  if (t < 128) sc_s[t] = 0.f;
  __syncthreads();
  float p[4][4];
#pragma unroll
  for (int i = 0; i < 4; ++i)
#pragma unroll
    for (int r = 0; r < 4; ++r) p[i][r] = 0.f;
#pragma unroll
  for (int j = 0; j < 4; ++j) {
    int col = wn * 64 + j * 16 + mr;
    float bias = bb[col];
    float wv = wp[col];
#pragma unroll
    for (int i = 0; i < 4; ++i) {
      int rowg = r0 + wm * 64 + i * 16 + quad * 4;
#pragma unroll
      for (int r = 0; r < 4; ++r) {
        float ho = fmaxf(acc[i][j][r] + bias, 0.f);
        Hout[(size_t)(rowg + r) * HD + col] = ho;
        p[i][r] += ho * wv;
      }
    }
  }
#pragma unroll
  for (int i = 0; i < 4; ++i)
#pragma unroll
    for (int r = 0; r < 4; ++r) {
#pragma unroll
      for (int m = 1; m <= 8; m <<= 1) p[i][r] += __shfl_xor(p[i][r], m, 16);
      if (mr == 0) atomicAdd(&sc_s[wm * 64 + i * 16 + quad * 4 + r], p[i][r]);
    }
  __syncthreads();
  if (t < 128) score[r0 + t] = sc_s[t];
}

// ---------------------------------------------------------------------------
// Per-graph: normalize scores, bitonic-sort alive-masked scores, threshold at
// kth largest, write gate = tanh(s) for kept nodes else 0.
__global__ __launch_bounds__(256) void topk_kernel(const float* __restrict__ score,
                                                   float* __restrict__ gate,
                                                   const float* __restrict__ wp,
                                                   int kk) {
  __shared__ float sc[NPG];
  __shared__ float srt[NPG];
  __shared__ float shv[1];
  int g = blockIdx.x, t = threadIdx.x;
  if (t == 0) {
    float ss = 0.f;
    for (int i = 0; i < HD; ++i) ss += wp[i] * wp[i];
    shv[0] = 1.0f / (sqrtf(ss) + 1e-16f);
  }
  __syncthreads();
  float inv = shv[0];
#pragma unroll
  for (int q = 0; q < 4; ++q) {
    int n = t + q * 256;
    float s = score[(g << 10) + n] * inv;
    sc[n] = s;
    srt[n] = (gate[(g << 10) + n] != 0.f) ? s : -3.402823466e38f;
  }
  __syncthreads();
  for (int k2 = 2; k2 <= NPG; k2 <<= 1) {
    for (int j = k2 >> 1; j > 0; j >>= 1) {
#pragma unroll
      for (int q = 0; q < 4; ++q) {
        int i = t + q * 256;
        int l = i ^ j;
        if (l > i) {
          float a = srt[i], b = srt[l];
          if ((a > b) == ((i & k2) == 0)) { srt[i] = b; srt[l] = a; }
        }
      }
      __syncthreads();
    }
  }
  float thr = srt[NPG - kk];
#pragma unroll
  for (int q = 0; q < 4; ++q) {
    int n = t + q * 256;
    float s = sc[n];
    bool sel = (gate[(g << 10) + n] != 0.f) && (s >= thr);
    gate[(g << 10) + n] = sel ? tanhf(s) : 0.f;
  }
}

// ---------------------------------------------------------------------------
// global mean pool of gate-weighted rows (divisor exactly K3), MLP, log_softmax
// 1024 threads: 8 row-chunks x 128 features, LDS partial reduction.
__global__ __launch_bounds__(1024) void final_kernel(const float* __restrict__ X,
                                                     const float* __restrict__ gate,
                                                     const float* __restrict__ Wf1,
                                                     const float* __restrict__ bf1,
                                                     const float* __restrict__ Wf2,
                                                     const float* __restrict__ bf2,
                                                     float* __restrict__ out) {
  __shared__ float gs[NPG];
  __shared__ float ps[8][HD];
  __shared__ float pl[HD];
  __shared__ float h1[64];
  __shared__ float lg[10];
  __shared__ float red[2];
  int g = blockIdx.x, t = threadIdx.x;
  gs[t] = gate[(g << 10) + t];
  __syncthreads();
  int c = t >> 7, f = t & 127;
  size_t base = (size_t)g * NPG * HD;
  float s = 0.f;
  for (int r = c * 128; r < c * 128 + 128; ++r)
    s += X[base + (size_t)r * HD + f] * gs[r];
  ps[c][f] = s;
  __syncthreads();
  if (t < HD) {
    float tot = 0.f;
#pragma unroll
    for (int cc = 0; cc < 8; ++cc) tot += ps[cc][t];
    pl[t] = tot / (float)KS3;
  }
  __syncthreads();
  if (t < 64) {
    float h = bf1[t];
    for (int ff = 0; ff < HD; ++ff) h += pl[ff] * Wf1[t * HD + ff];
    h1[t] = fmaxf(h, 0.f);
  }
  __syncthreads();
  if (t < 10) {
    float z = bf2[t];
    for (int j = 0; j < 64; ++j) z += h1[j] * Wf2[t * 64 + j];
    lg[t] = z;
  }
  __syncthreads();
  if (t == 0) {
    float m = lg[0];
    for (int cc = 1; cc < 10; ++cc) m = fmaxf(m, lg[cc]);
    float ssum = 0.f;
    for (int cc = 0; cc < 10; ++cc) ssum += expf(lg[cc] - m);
    red[0] = m; red[1] = logf(ssum);
  }
  __syncthreads();
  if (t < 10) out[g * 10 + t] = lg[t] - red[0] - red[1];
}

// ---------------------------------------------------------------------------
extern "C" void kernel_launch(void* const* d_in, const int* in_sizes, int n_in,
                              void* d_out, int out_size, void* d_ws, size_t ws_size,
                              hipStream_t stream) {
  const float* x  = (const float*)d_in[0];
  int* ei         = (int*)d_in[1];          // src half becomes CSR after csr_build
  const float* Wl[3]  = {(const float*)d_in[2], (const float*)d_in[6],  (const float*)d_in[10]};
  const float* blv[3] = {(const float*)d_in[3], (const float*)d_in[7],  (const float*)d_in[11]};
  const float* Wr[3]  = {(const float*)d_in[4], (const float*)d_in[8],  (const float*)d_in[12]};
  const float* wp[3]  = {(const float*)d_in[5], (const float*)d_in[9],  (const float*)d_in[13]};
  const float* Wf1 = (const float*)d_in[14];
  const float* bf1 = (const float*)d_in[15];
  const float* Wf2 = (const float*)d_in[16];
  const float* bf2 = (const float*)d_in[17];
  float* out = (float*)d_out;

  // workspace: bufA (64MB) | bufB (64MB) | gate (512KB) | score (512KB) | Wcvt (384KB)
  float* bufA  = (float*)d_ws;
  float* bufB  = bufA + (size_t)NN * HD;
  float* gate  = bufB + (size_t)NN * HD;
  float* score = gate + NN;
  _Float16* Wcvt = (_Float16*)(score + NN);

  init_gate<<<NN / 256, 256, 0, stream>>>(gate);
  wconv<<<384, 256, 0, stream>>>(Wl[0], Wr[0], Wl[1], Wr[1], Wl[2], Wr[2], Wcvt);
  csr_build<<<NGPH, 512, 0, stream>>>(ei);

  // L1: x -> mean(bufA) -> gemm in-place bufA (+score) -> topk (gate only)
  agg2_kernel<<<NN / 8, 256, 0, stream>>>(x, ei, gate, bufA);
  gemm_mfma<<<NN / 128, 256, 0, stream>>>(bufA, x, Wcvt, blv[0], wp[0], gate, bufA, score);
  topk_kernel<<<NGPH, 256, 0, stream>>>(score, gate, wp[0], KS1);
  // L2
  agg2_kernel<<<NN / 8, 256, 0, stream>>>(bufA, ei, gate, bufB);
  gemm_mfma<<<NN / 128, 256, 0, stream>>>(bufB, bufA, Wcvt + 65536, blv[1], wp[1], gate, bufB, score);
  topk_kernel<<<NGPH, 256, 0, stream>>>(score, gate, wp[1], KS2);
  // L3
  agg2_kernel<<<NN / 8, 256, 0, stream>>>(bufB, ei, gate, bufA);
  gemm_mfma<<<NN / 128, 256, 0, stream>>>(bufA, bufB, Wcvt + 131072, blv[2], wp[2], gate, bufA, score);
  topk_kernel<<<NGPH, 256, 0, stream>>>(score, gate, wp[2], KS3);

  final_kernel<<<NGPH, 1024, 0, stream>>>(bufA, gate, Wf1, bf1, Wf2, bf2, out);
}